// Round 9
// baseline (171.225 us; speedup 1.0000x reference)
//
#include <hip/hip_runtime.h>

namespace {
constexpr int kB = 16, kT = 2048, kC = 512, kH = 4, kU = 250, kDH = 128;
constexpr int kTW = 32;          // t per band chunk
}

typedef __attribute__((ext_vector_type(8))) short short8;
typedef __attribute__((ext_vector_type(4))) float float4v;

// packed f32x2 -> bf16x2 (RNE), single VALU op; lo = src0, hi = src1
__device__ __forceinline__ unsigned int pk_bf16(float lo, float hi) {
    unsigned int r;
    asm volatile("v_cvt_pk_bf16_f32 %0, %1, %2" : "=v"(r) : "v"(lo), "v"(hi));
    return r;
}
__device__ __forceinline__ float exp2_fast(float x) {   // 2^x, raw v_exp
    float r;
    asm volatile("v_exp_f32 %0, %1" : "=v"(r) : "v"(x));
    return r;
}

// ---------------- K1: alpha branch (round-0 proven) + NATURAL-layout V emit ----------------
// block = 4 waves = 32 consecutive t of one b; wave = 8 t rows, lane owns 8 c.
// V emit: Vn[b][t][c] bf16 -- one fully-coalesced 1-KB store per t-row (exact dual
// of the loads). Round-7/8 layouts scattered each store across 64 cache lines
// (512-B lane stride); natural layout keeps lines block-local AND coalesced.
__global__ __launch_bounds__(256) void k1_alpha(
    const float* __restrict__ hid, const float* __restrict__ mask,
    const float* __restrict__ conv_w, const float* __restrict__ conv_b,
    const float* __restrict__ lin_w, const float* __restrict__ lin_b,
    float* __restrict__ alpha_raw, unsigned short* __restrict__ Vn)
{
    __shared__ float halo[4][2][512];   // 16 KB: [wave][first/last core row][c]
    const int wave = threadIdx.x >> 6, lane = threadIdx.x & 63;
    const int b = blockIdx.x >> 6;             // 64 blocks per b
    const int tblk = (blockIdx.x & 63) << 5;   // 32 t per block
    const int t0 = tblk + wave * 8;
    const int c0 = lane * 8;

    float cw[24], cb[8], lw[8];
    #pragma unroll
    for (int i = 0; i < 6; i++) *(float4*)&cw[i*4] = ((const float4*)(conv_w + c0*3))[i];
    *(float4*)&cb[0] = *(const float4*)(conv_b + c0);
    *(float4*)&cb[4] = *(const float4*)(conv_b + c0 + 4);
    *(float4*)&lw[0] = *(const float4*)(lin_w + c0);
    *(float4*)&lw[4] = *(const float4*)(lin_w + c0 + 4);
    const float lb = lin_b[0];

    float r[10][8];
    const float* base = hid + ((size_t)b * kT + t0) * kC + c0;
    #pragma unroll
    for (int i = 1; i <= 8; i++) {              // core rows t0 .. t0+7
        const float* p = base + (ptrdiff_t)(i - 1) * kC;
        *(float4*)&r[i][0] = *(const float4*)p;
        *(float4*)&r[i][4] = *(const float4*)(p + 4);
    }
    // natural-layout V emit: one coalesced 16-B store per row (1 KB per wave-instr)
    #pragma unroll
    for (int j = 1; j <= 8; j++) {
        unsigned int vw[4];
        vw[0] = pk_bf16(r[j][0], r[j][1]);
        vw[1] = pk_bf16(r[j][2], r[j][3]);
        vw[2] = pk_bf16(r[j][4], r[j][5]);
        vw[3] = pk_bf16(r[j][6], r[j][7]);
        *(uint4*)(Vn + ((size_t)b * kT + t0 + j - 1) * kC + c0) = *(const uint4*)vw;
    }

    // publish boundary core rows
    *(float4*)&halo[wave][0][c0]     = *(float4*)&r[1][0];
    *(float4*)&halo[wave][0][c0 + 4] = *(float4*)&r[1][4];
    *(float4*)&halo[wave][1][c0]     = *(float4*)&r[8][0];
    *(float4*)&halo[wave][1][c0 + 4] = *(float4*)&r[8][4];

    // block-boundary halos from HBM (or zeros at sequence edges)
    if (wave == 0) {
        if (tblk > 0) {
            const float* p = base - kC;
            *(float4*)&r[0][0] = *(const float4*)p;
            *(float4*)&r[0][4] = *(const float4*)(p + 4);
        } else {
            #pragma unroll
            for (int j = 0; j < 8; j++) r[0][j] = 0.f;
        }
    }
    if (wave == 3) {
        if (tblk + 32 < kT) {
            const float* p = base + 8 * kC;
            *(float4*)&r[9][0] = *(const float4*)p;
            *(float4*)&r[9][4] = *(const float4*)(p + 4);
        } else {
            #pragma unroll
            for (int j = 0; j < 8; j++) r[9][j] = 0.f;
        }
    }
    __syncthreads();
    if (wave > 0) {
        *(float4*)&r[0][0] = *(float4*)&halo[wave - 1][1][c0];
        *(float4*)&r[0][4] = *(float4*)&halo[wave - 1][1][c0 + 4];
    }
    if (wave < 3) {
        *(float4*)&r[9][0] = *(float4*)&halo[wave + 1][0][c0];
        *(float4*)&r[9][4] = *(float4*)&halo[wave + 1][0][c0 + 4];
    }

    float sums[8];
    #pragma unroll
    for (int j = 0; j < 8; j++) {
        float acc = 0.f;
        #pragma unroll
        for (int k = 0; k < 8; k++) {
            float m = fmaf(r[j][k], cw[k*3],
                      fmaf(r[j+1][k], cw[k*3+1],
                      fmaf(r[j+2][k], cw[k*3+2], cb[k])));
            float v = m + r[j+1][k];          // memory + context
            v = v > 0.f ? v : 0.f;            // relu
            acc = fmaf(v, lw[k], acc);
        }
        #pragma unroll
        for (int off = 32; off >= 1; off >>= 1) acc += __shfl_xor(acc, off, 64);
        sums[j] = acc;
    }
    if (lane == 0) {
        #pragma unroll
        for (int j = 0; j < 8; j++) {
            float s = sums[j] + lb;
            float a = 1.f / (1.f + expf(-s));  // relu(sigmoid*1-0) == sigmoid
            alpha_raw[(size_t)b * kT + t0 + j] = a * mask[(size_t)b * kT + t0 + j];
        }
    }
}

// ---------------- K2: per-b scan (once) ----------------
__global__ __launch_bounds__(256) void k2_scan(
    const float* __restrict__ alpha_raw, const float* __restrict__ mask,
    const int* __restrict__ target,
    float* __restrict__ al, float* __restrict__ out_tok, float* __restrict__ out_alpha)
{
    __shared__ float woff[4];
    __shared__ float s_tot;
    const int b = blockIdx.x, tid = threadIdx.x;
    const int wave = tid >> 6, lane = tid & 63;

    float a[8], m[8];
    const float* ar = alpha_raw + (size_t)b * kT + tid * 8;
    const float* mr = mask + (size_t)b * kT + tid * 8;
    *(float4*)&a[0] = *(const float4*)ar;
    *(float4*)&a[4] = *(const float4*)(ar + 4);
    *(float4*)&m[0] = *(const float4*)mr;
    *(float4*)&m[4] = *(const float4*)(mr + 4);

    float pre[8]; float run = 0.f;
    #pragma unroll
    for (int j = 0; j < 8; j++) { run += a[j]; pre[j] = run; }
    float sc = run;
    #pragma unroll
    for (int off = 1; off <= 32; off <<= 1) {
        float v = __shfl_up(sc, off, 64);
        sc = (lane >= off) ? sc + v : sc;
    }
    if (lane == 63) woff[wave] = sc;
    __syncthreads();
    if (tid == 0) {
        float r2 = 0.f;
        #pragma unroll
        for (int w = 0; w < 4; w++) { float x = woff[w]; woff[w] = r2; r2 += x; }
        s_tot = r2;
    }
    __syncthreads();
    const float tot = s_tot;
    const float scale = (tot != 0.f) ? ((float)target[b] / tot) : 0.f;
    const float basev = woff[wave] + (sc - run);

    float alv[8], oav[8];
    #pragma unroll
    for (int j = 0; j < 8; j++) {
        alv[j] = (m[j] > 0.f) ? (basev + pre[j]) * scale : 1.0e30f;
        oav[j] = a[j] * scale;
    }
    float* alw = al + (size_t)b * kT + tid * 8;
    float* oaw = out_alpha + (size_t)b * kT + tid * 8;
    *(float4*)alw       = *(const float4*)&alv[0];
    *(float4*)(alw + 4) = *(const float4*)&alv[4];
    *(float4*)oaw       = *(const float4*)&oav[0];
    *(float4*)(oaw + 4) = *(const float4*)&oav[4];
    if (tid == 0) out_tok[b] = tot;
}

// ---------------- K3: banded MFMA attention, per-wave LDS transpose staging ----------------
// 1024 blocks x 256 thr, launch_bounds(256,4). XCD-pairing decode: i = bh*16 + m*8 + x
// -> ut = 2x + m, so adjacent u-tiles (2x, 2x+1) of one (b,h) land on XCD x (bands
// overlap most between neighbors -> L2 reuse). Wave owns 16 u x 32 c. Tight per-lane
// bands (round-8 proven). Per 32-t chunk: 8 uint loads from Vn[b][t][c] (coalesced),
// shfl_xor(16) pairing + ds_write_b32 into a wave-PRIVATE LDS tile (no barriers),
// b128 fragment reads, 2 MFMA. P computed while loads fly.
__global__ __launch_bounds__(256, 4) void k3_attn(
    const unsigned short* __restrict__ Vn, const float* __restrict__ al,
    const float* __restrict__ sigma, float* __restrict__ out_ac)
{
    __shared__ float al_s[kT];                    // 8 KB
    __shared__ unsigned short vt[4][32][40];      // 10 KB: [wave][c_local][32t + pad]

    const int i = blockIdx.x;
    const int bh = i >> 4, m = (i >> 3) & 1, x = i & 7;
    const int ut = 2 * x + m;
    const int b = bh >> 2, h = bh & 3;
    const int tid = threadIdx.x;
    const int wave = tid >> 6, lane = tid & 63;
    const int lm = lane & 15, quad = lane >> 4;
    const int u0 = ut * 16;
    const int cb = h * kDH + wave * 32;
    const float sig = sigma[h];
    const float sigL = sig * 1.2011224f;          // sig * sqrt(log2 e)

    {   // stage alignment into LDS (2 x float4 per thread)
        const float4* alg = (const float4*)(al + (size_t)b * kT);
        ((float4*)al_s)[tid]       = alg[tid];
        ((float4*)al_s)[tid + 256] = alg[tid + 256];
    }
    __syncthreads();

    // per-lane u: exact softmax max via binary search (al_s monotone)
    const float du = (float)(u0 + lm) + 0.5f;
    const float duL = du * sigL;
    int pos = 0;
    #pragma unroll
    for (int stp = 1024; stp >= 1; stp >>= 1) {
        int np = pos + stp;
        pos = (al_s[np - 1] < du) ? np : pos;
    }
    float d1 = (pos < kT) ? al_s[pos] - du : 3.0e30f;
    float d0 = (pos > 0) ? du - al_s[pos - 1] : 3.0e30f;
    float dmin = fminf(d0, d1);
    float dmn = fminf(dmin, 1.0e4f);
    float ms = dmn * sigL;
    const float mu_pos = ms * ms;                 // = -max_score in log2 units

    // per-lane tight band: |du - al| <= sqrt(dmin_l^2 + 21/sig^2); wave = union
    const float c21 = (sig > 1e-3f) ? 21.0f / (sig * sig) : 9.0e60f;
    const float bnd = sqrtf(fmaf(dmn, dmn, c21));
    float lo_l = du - bnd, hi_l = du + bnd;
    #pragma unroll
    for (int off = 8; off >= 1; off >>= 1) {
        lo_l = fminf(lo_l, __shfl_xor(lo_l, off, 64));
        hi_l = fmaxf(hi_l, __shfl_xor(hi_l, off, 64));
    }
    int p_lo = 0, p_hi = 0;
    #pragma unroll
    for (int stp = 1024; stp >= 1; stp >>= 1) {
        int n1 = p_lo + stp; p_lo = (al_s[n1 - 1] < lo_l) ? n1 : p_lo;
        int n2 = p_hi + stp; p_hi = (al_s[n2 - 1] < hi_l) ? n2 : p_hi;
    }
    const int ks_lo = p_lo >> 5;
    const int ks_end = (p_hi + 31) >> 5;

    float4v acc0 = (float4v)(0.f), acc1 = (float4v)(0.f);
    float lsum = 0.f;

    // staging source: lane reads uint (2 c) of row t = kb + ip*4 + trow
    const int c2l = (lm) * 2;                     // local c pair base (0..30)
    const int trow = quad;                        // 0..3
    const unsigned short* vsrc = Vn + (size_t)b * kT * kC + cb + c2l;

    for (int kg = ks_lo; kg < ks_end; kg++) {
        const int kb = kg * kTW;

        // (1) issue the 8 staging loads
        unsigned int vv[8];
        #pragma unroll
        for (int ip = 0; ip < 8; ip++)
            vv[ip] = *(const unsigned int*)(vsrc + (size_t)(kb + ip * 4 + trow) * kC);

        // (2) P computation (independent of loads -- overlaps their latency)
        float alvv[8];
        *(float4*)&alvv[0] = *(const float4*)&al_s[kb + quad * 8];
        *(float4*)&alvv[4] = *(const float4*)&al_s[kb + quad * 8 + 4];
        float ev[8];
        #pragma unroll
        for (int j = 0; j < 8; j++) {
            float d = fmaf(-alvv[j], sigL, duL);      // (du - al) * sigL
            float e = exp2_fast(fmaf(-d, d, mu_pos)); // 2^(mu' - d'^2) <= 1
            lsum += e;
            ev[j] = e;
        }
        union { short8 s; unsigned int w[4]; } af;
        af.w[0] = pk_bf16(ev[0], ev[1]);
        af.w[1] = pk_bf16(ev[2], ev[3]);
        af.w[2] = pk_bf16(ev[4], ev[5]);
        af.w[3] = pk_bf16(ev[6], ev[7]);

        // (3) pair t/t+1 via shfl_xor(16), write wave-private LDS transpose
        #pragma unroll
        for (int ip = 0; ip < 8; ip++) {
            unsigned int v = vv[ip];
            unsigned int p = (unsigned int)__shfl_xor((int)v, 16, 64);
            const int tp = ip * 2 + (trow >> 1);
            unsigned int w; int c_w;
            if ((trow & 1) == 0) {   // even-t holder: produce word for c = c2l
                w = (v & 0xffffu) | (p << 16);
                c_w = c2l;
            } else {                  // odd-t holder: produce word for c = c2l+1
                w = (p >> 16) | (v & 0xffff0000u);
                c_w = c2l + 1;
            }
            *(unsigned int*)&vt[wave][c_w][tp * 2] = w;
        }

        // (4) fragments from LDS (wave-private, compiler orders via lgkmcnt)
        short8 bf0 = *(const short8*)&vt[wave][lm][quad * 8];
        short8 bf1 = *(const short8*)&vt[wave][lm + 16][quad * 8];
        acc0 = __builtin_amdgcn_mfma_f32_16x16x32_bf16(af.s, bf0, acc0, 0, 0, 0);
        acc1 = __builtin_amdgcn_mfma_f32_16x16x32_bf16(af.s, bf1, acc1, 0, 0, 0);
    }

    // epilogue: full P-row sums (over quads), normalize, direct store (disjoint)
    float lv = lsum;
    lv += __shfl_xor(lv, 16, 64);
    lv += __shfl_xor(lv, 32, 64);        // every lane: full l for u = u0 + lm
    #pragma unroll
    for (int r = 0; r < 4; r++) {
        const int ur = quad * 4 + r;
        float rl = __shfl(lv, ur, 64);   // l for u = u0 + ur
        float linv = (rl > 1e-30f) ? 1.f / rl : 0.f;
        const int u = u0 + ur;
        if (u < kU) {
            float* dst = out_ac + ((size_t)(b * kU + u)) * kC + cb + lm;
            dst[0]  = acc0[r] * linv;
            dst[16] = acc1[r] * linv;
        }
    }
}

extern "C" void kernel_launch(void* const* d_in, const int* in_sizes, int n_in,
                              void* d_out, int out_size, void* d_ws, size_t ws_size,
                              hipStream_t stream) {
    const float* hid    = (const float*)d_in[0];
    const float* mask   = (const float*)d_in[1];
    const int*   tgt    = (const int*)d_in[2];
    // d_in[3] = max_token scalar (compile-time kU=250)
    const float* conv_w = (const float*)d_in[4];
    const float* conv_b = (const float*)d_in[5];
    const float* lin_w  = (const float*)d_in[6];
    const float* lin_b  = (const float*)d_in[7];
    const float* sigma  = (const float*)d_in[8];
    // d_in[9] = sigma_bias: constant over t -> cancels in softmax; unused.

    float* alpha_raw = (float*)d_ws;                                   // [B*T] f32
    float* al        = (float*)((char*)d_ws + 131072);                 // [B*T] f32
    unsigned short* Vn = (unsigned short*)((char*)d_ws + 262144);      // [B][T][C] bf16, 33.6 MB

    float* out_ac    = (float*)d_out;                    // [B, U, C]
    float* out_tok   = out_ac + (size_t)kB * kU * kC;    // [B]
    float* out_alpha = out_tok + kB;                     // [B, T]

    k1_alpha<<<kB * kT / 32, 256, 0, stream>>>(hid, mask, conv_w, conv_b, lin_w, lin_b,
                                               alpha_raw, Vn);
    k2_scan<<<kB, 256, 0, stream>>>(alpha_raw, mask, tgt, al, out_tok, out_alpha);
    k3_attn<<<1024, 256, 0, stream>>>(Vn, al, sigma, out_ac);
}

// Round 10
// 157.291 us; speedup vs baseline: 1.0886x; 1.0886x over previous
//
#include <hip/hip_runtime.h>

namespace {
constexpr int kB = 16, kT = 2048, kC = 512, kH = 4, kU = 250, kDH = 128;
constexpr int kTW = 32;          // t per band chunk
}

typedef __attribute__((ext_vector_type(8))) short short8;
typedef __attribute__((ext_vector_type(4))) float float4v;

// packed f32x2 -> bf16x2 (RNE), single VALU op; lo = src0, hi = src1
__device__ __forceinline__ unsigned int pk_bf16(float lo, float hi) {
    unsigned int r;
    asm("v_cvt_pk_bf16_f32 %0, %1, %2" : "=v"(r) : "v"(lo), "v"(hi));
    return r;
}
__device__ __forceinline__ float exp2_fast(float x) {   // 2^x, raw v_exp
    float r;
    asm("v_exp_f32 %0, %1" : "=v"(r) : "v"(x));
    return r;
}

// ---------------- K1: alpha prediction branch (round-0 proven, unmodified) ----------------
// block = 4 waves = 32 consecutive t of one b. Each wave loads its 8 core rows;
// interior halo rows exchanged via LDS (only block-boundary halos hit HBM).
// Side effect: leaves hidden L3-resident for k3.
__global__ __launch_bounds__(256) void k1_alpha(
    const float* __restrict__ hid, const float* __restrict__ mask,
    const float* __restrict__ conv_w, const float* __restrict__ conv_b,
    const float* __restrict__ lin_w, const float* __restrict__ lin_b,
    float* __restrict__ alpha_raw)
{
    __shared__ float halo[4][2][512];   // 16 KB: [wave][first/last core row][c]
    const int wave = threadIdx.x >> 6, lane = threadIdx.x & 63;
    const int b = blockIdx.x >> 6;             // 64 blocks per b
    const int tblk = (blockIdx.x & 63) << 5;   // 32 t per block
    const int t0 = tblk + wave * 8;
    const int c0 = lane * 8;

    float cw[24], cb[8], lw[8];
    #pragma unroll
    for (int i = 0; i < 6; i++) *(float4*)&cw[i*4] = ((const float4*)(conv_w + c0*3))[i];
    *(float4*)&cb[0] = *(const float4*)(conv_b + c0);
    *(float4*)&cb[4] = *(const float4*)(conv_b + c0 + 4);
    *(float4*)&lw[0] = *(const float4*)(lin_w + c0);
    *(float4*)&lw[4] = *(const float4*)(lin_w + c0 + 4);
    const float lb = lin_b[0];

    float r[10][8];
    const float* base = hid + ((size_t)b * kT + t0) * kC + c0;
    #pragma unroll
    for (int i = 1; i <= 8; i++) {              // core rows t0 .. t0+7
        const float* p = base + (ptrdiff_t)(i - 1) * kC;
        *(float4*)&r[i][0] = *(const float4*)p;
        *(float4*)&r[i][4] = *(const float4*)(p + 4);
    }
    // publish boundary core rows
    *(float4*)&halo[wave][0][c0]     = *(float4*)&r[1][0];
    *(float4*)&halo[wave][0][c0 + 4] = *(float4*)&r[1][4];
    *(float4*)&halo[wave][1][c0]     = *(float4*)&r[8][0];
    *(float4*)&halo[wave][1][c0 + 4] = *(float4*)&r[8][4];

    // block-boundary halos from HBM (or zeros at sequence edges)
    if (wave == 0) {
        if (tblk > 0) {
            const float* p = base - kC;
            *(float4*)&r[0][0] = *(const float4*)p;
            *(float4*)&r[0][4] = *(const float4*)(p + 4);
        } else {
            #pragma unroll
            for (int j = 0; j < 8; j++) r[0][j] = 0.f;
        }
    }
    if (wave == 3) {
        if (tblk + 32 < kT) {
            const float* p = base + 8 * kC;
            *(float4*)&r[9][0] = *(const float4*)p;
            *(float4*)&r[9][4] = *(const float4*)(p + 4);
        } else {
            #pragma unroll
            for (int j = 0; j < 8; j++) r[9][j] = 0.f;
        }
    }
    __syncthreads();
    if (wave > 0) {
        *(float4*)&r[0][0] = *(float4*)&halo[wave - 1][1][c0];
        *(float4*)&r[0][4] = *(float4*)&halo[wave - 1][1][c0 + 4];
    }
    if (wave < 3) {
        *(float4*)&r[9][0] = *(float4*)&halo[wave + 1][0][c0];
        *(float4*)&r[9][4] = *(float4*)&halo[wave + 1][0][c0 + 4];
    }

    float sums[8];
    #pragma unroll
    for (int j = 0; j < 8; j++) {
        float acc = 0.f;
        #pragma unroll
        for (int k = 0; k < 8; k++) {
            float m = fmaf(r[j][k], cw[k*3],
                      fmaf(r[j+1][k], cw[k*3+1],
                      fmaf(r[j+2][k], cw[k*3+2], cb[k])));
            float v = m + r[j+1][k];          // memory + context
            v = v > 0.f ? v : 0.f;            // relu
            acc = fmaf(v, lw[k], acc);
        }
        #pragma unroll
        for (int off = 32; off >= 1; off >>= 1) acc += __shfl_xor(acc, off, 64);
        sums[j] = acc;
    }
    if (lane == 0) {
        #pragma unroll
        for (int j = 0; j < 8; j++) {
            float s = sums[j] + lb;
            float a = 1.f / (1.f + expf(-s));  // relu(sigmoid*1-0) == sigmoid
            alpha_raw[(size_t)b * kT + t0 + j] = a * mask[(size_t)b * kT + t0 + j];
        }
    }
}

// ---------------- K2: per-b scan (once) ----------------
__global__ __launch_bounds__(256) void k2_scan(
    const float* __restrict__ alpha_raw, const float* __restrict__ mask,
    const int* __restrict__ target,
    float* __restrict__ al, float* __restrict__ out_tok, float* __restrict__ out_alpha)
{
    __shared__ float woff[4];
    __shared__ float s_tot;
    const int b = blockIdx.x, tid = threadIdx.x;
    const int wave = tid >> 6, lane = tid & 63;

    float a[8], m[8];
    const float* ar = alpha_raw + (size_t)b * kT + tid * 8;
    const float* mr = mask + (size_t)b * kT + tid * 8;
    *(float4*)&a[0] = *(const float4*)ar;
    *(float4*)&a[4] = *(const float4*)(ar + 4);
    *(float4*)&m[0] = *(const float4*)mr;
    *(float4*)&m[4] = *(const float4*)(mr + 4);

    float pre[8]; float run = 0.f;
    #pragma unroll
    for (int j = 0; j < 8; j++) { run += a[j]; pre[j] = run; }
    float sc = run;
    #pragma unroll
    for (int off = 1; off <= 32; off <<= 1) {
        float v = __shfl_up(sc, off, 64);
        sc = (lane >= off) ? sc + v : sc;
    }
    if (lane == 63) woff[wave] = sc;
    __syncthreads();
    if (tid == 0) {
        float r2 = 0.f;
        #pragma unroll
        for (int w = 0; w < 4; w++) { float x = woff[w]; woff[w] = r2; r2 += x; }
        s_tot = r2;
    }
    __syncthreads();
    const float tot = s_tot;
    const float scale = (tot != 0.f) ? ((float)target[b] / tot) : 0.f;
    const float basev = woff[wave] + (sc - run);

    float alv[8], oav[8];
    #pragma unroll
    for (int j = 0; j < 8; j++) {
        alv[j] = (m[j] > 0.f) ? (basev + pre[j]) * scale : 1.0e30f;
        oav[j] = a[j] * scale;
    }
    float* alw = al + (size_t)b * kT + tid * 8;
    float* oaw = out_alpha + (size_t)b * kT + tid * 8;
    *(float4*)alw       = *(const float4*)&alv[0];
    *(float4*)(alw + 4) = *(const float4*)&alv[4];
    *(float4*)oaw       = *(const float4*)&oav[0];
    *(float4*)(oaw + 4) = *(const float4*)&oav[4];
    if (tid == 0) out_tok[b] = tot;
}

// ---------------- K3: banded MFMA attention, V straight from L3-hot hidden ----------------
// grid (ut=16, h=4, b=16) = 1024 blocks x 256 thr, launch_bounds(256,4) -> 16 waves/CU.
// Wave owns 16 u x 32 c. Tight per-lane bands (round-8 proven). Per 32-t chunk:
// P in-register (log2-domain exp); V fragments = 16 scalar f32 loads per lane from
// hidden[b][t][cb+lm] (k1 just streamed hidden -> L3-resident; per-instr 4 rows x
// 64-B segments, all L3 hits), pk_bf16 in-register, 2 MFMA. No V materialization,
// no LDS staging, no barriers in the loop.
__global__ __launch_bounds__(256, 4) void k3_attn(
    const float* __restrict__ hid, const float* __restrict__ al,
    const float* __restrict__ sigma, float* __restrict__ out_ac)
{
    __shared__ float al_s[kT];   // 8 KB

    const int ut = blockIdx.x, h = blockIdx.y, b = blockIdx.z;
    const int tid = threadIdx.x;
    const int wave = tid >> 6, lane = tid & 63;
    const int lm = lane & 15, quad = lane >> 4;
    const int u0 = ut * 16;
    const int cb = h * kDH + wave * 32;
    const float sig = sigma[h];
    const float sigL = sig * 1.2011224f;          // sig * sqrt(log2 e)

    {   // stage alignment into LDS (2 x float4 per thread)
        const float4* alg = (const float4*)(al + (size_t)b * kT);
        ((float4*)al_s)[tid]       = alg[tid];
        ((float4*)al_s)[tid + 256] = alg[tid + 256];
    }
    __syncthreads();

    // per-lane u: exact softmax max via binary search (al_s monotone)
    const float du = (float)(u0 + lm) + 0.5f;
    const float duL = du * sigL;
    int pos = 0;
    #pragma unroll
    for (int stp = 1024; stp >= 1; stp >>= 1) {
        int np = pos + stp;
        pos = (al_s[np - 1] < du) ? np : pos;
    }
    float d1 = (pos < kT) ? al_s[pos] - du : 3.0e30f;
    float d0 = (pos > 0) ? du - al_s[pos - 1] : 3.0e30f;
    float dmin = fminf(d0, d1);
    float dmn = fminf(dmin, 1.0e4f);
    float ms = dmn * sigL;
    const float mu_pos = ms * ms;                 // = -max_score in log2 units

    // per-lane tight band: |du - al| <= sqrt(dmin_l^2 + 21/sig^2); wave = union
    const float c21 = (sig > 1e-3f) ? 21.0f / (sig * sig) : 9.0e60f;
    const float bnd = sqrtf(fmaf(dmn, dmn, c21));
    float lo_l = du - bnd, hi_l = du + bnd;
    #pragma unroll
    for (int off = 8; off >= 1; off >>= 1) {
        lo_l = fminf(lo_l, __shfl_xor(lo_l, off, 64));
        hi_l = fmaxf(hi_l, __shfl_xor(hi_l, off, 64));
    }
    int p_lo = 0, p_hi = 0;
    #pragma unroll
    for (int stp = 1024; stp >= 1; stp >>= 1) {
        int n1 = p_lo + stp; p_lo = (al_s[n1 - 1] < lo_l) ? n1 : p_lo;
        int n2 = p_hi + stp; p_hi = (al_s[n2 - 1] < hi_l) ? n2 : p_hi;
    }
    const int ks_lo = p_lo >> 5;
    const int ks_end = (p_hi + 31) >> 5;

    float4v acc0 = (float4v)(0.f), acc1 = (float4v)(0.f);
    float lsum = 0.f;

    // V source: lane reads column c = cb (+16) + lm of rows t = kb + quad*8 + j
    const float* vcol0 = hid + (size_t)b * kT * kC + cb + lm;
    const float* vcol1 = vcol0 + 16;

    #pragma unroll 2
    for (int kg = ks_lo; kg < ks_end; kg++) {
        const int kb = kg * kTW;
        const int tb0 = kb + quad * 8;

        // (1) issue the 16 V loads first (independent; L3 hits)
        float v0[8], v1[8];
        #pragma unroll
        for (int j = 0; j < 8; j++) {
            v0[j] = vcol0[(size_t)(tb0 + j) * kC];
            v1[j] = vcol1[(size_t)(tb0 + j) * kC];
        }

        // (2) P computation overlaps load latency
        float alvv[8];
        *(float4*)&alvv[0] = *(const float4*)&al_s[kb + quad * 8];
        *(float4*)&alvv[4] = *(const float4*)&al_s[kb + quad * 8 + 4];
        float ev[8];
        #pragma unroll
        for (int j = 0; j < 8; j++) {
            float d = fmaf(-alvv[j], sigL, duL);      // (du - al) * sigL
            float e = exp2_fast(fmaf(-d, d, mu_pos)); // 2^(mu' - d'^2) <= 1
            lsum += e;
            ev[j] = e;
        }
        union { short8 s; unsigned int w[4]; } af, bf0, bf1;
        af.w[0] = pk_bf16(ev[0], ev[1]);
        af.w[1] = pk_bf16(ev[2], ev[3]);
        af.w[2] = pk_bf16(ev[4], ev[5]);
        af.w[3] = pk_bf16(ev[6], ev[7]);

        // (3) pack V fragments
        #pragma unroll
        for (int p2 = 0; p2 < 4; p2++) {
            bf0.w[p2] = pk_bf16(v0[2*p2], v0[2*p2 + 1]);
            bf1.w[p2] = pk_bf16(v1[2*p2], v1[2*p2 + 1]);
        }
        acc0 = __builtin_amdgcn_mfma_f32_16x16x32_bf16(af.s, bf0.s, acc0, 0, 0, 0);
        acc1 = __builtin_amdgcn_mfma_f32_16x16x32_bf16(af.s, bf1.s, acc1, 0, 0, 0);
    }

    // epilogue: full P-row sums (over quads), normalize, direct store (disjoint)
    float lv = lsum;
    lv += __shfl_xor(lv, 16, 64);
    lv += __shfl_xor(lv, 32, 64);        // every lane: full l for u = u0 + lm
    #pragma unroll
    for (int r = 0; r < 4; r++) {
        const int ur = quad * 4 + r;
        float rl = __shfl(lv, ur, 64);   // l for u = u0 + ur
        float linv = (rl > 1e-30f) ? 1.f / rl : 0.f;
        const int u = u0 + ur;
        if (u < kU) {
            float* dst = out_ac + ((size_t)(b * kU + u)) * kC + cb + lm;
            dst[0]  = acc0[r] * linv;
            dst[16] = acc1[r] * linv;
        }
    }
}

extern "C" void kernel_launch(void* const* d_in, const int* in_sizes, int n_in,
                              void* d_out, int out_size, void* d_ws, size_t ws_size,
                              hipStream_t stream) {
    const float* hid    = (const float*)d_in[0];
    const float* mask   = (const float*)d_in[1];
    const int*   tgt    = (const int*)d_in[2];
    // d_in[3] = max_token scalar (compile-time kU=250)
    const float* conv_w = (const float*)d_in[4];
    const float* conv_b = (const float*)d_in[5];
    const float* lin_w  = (const float*)d_in[6];
    const float* lin_b  = (const float*)d_in[7];
    const float* sigma  = (const float*)d_in[8];
    // d_in[9] = sigma_bias: constant over t -> cancels in softmax; unused.

    float* alpha_raw = (float*)d_ws;                       // [B*T] f32
    float* al        = (float*)((char*)d_ws + 131072);     // [B*T] f32

    float* out_ac    = (float*)d_out;                    // [B, U, C]
    float* out_tok   = out_ac + (size_t)kB * kU * kC;    // [B]
    float* out_alpha = out_tok + kB;                     // [B, T]

    k1_alpha<<<kB * kT / 32, 256, 0, stream>>>(hid, mask, conv_w, conv_b, lin_w, lin_b,
                                               alpha_raw);
    k2_scan<<<kB, 256, 0, stream>>>(alpha_raw, mask, tgt, al, out_tok, out_alpha);
    k3_attn<<<dim3(16, kH, kB), 256, 0, stream>>>(hid, al, sigma, out_ac);
}